// Round 11
// baseline (117.424 us; speedup 1.0000x reference)
//
#include <hip/hip_runtime.h>

typedef unsigned short u16;
typedef unsigned int u32;
typedef float f32x4 __attribute__((ext_vector_type(4)));
typedef float f32x16 __attribute__((ext_vector_type(16)));
typedef unsigned int u32x4 __attribute__((ext_vector_type(4)));
typedef unsigned int u32x2 __attribute__((ext_vector_type(2)));
typedef unsigned short u16x8 __attribute__((ext_vector_type(8)));
typedef unsigned short u16x4 __attribute__((ext_vector_type(4)));

#define DEV static __device__ __forceinline__

constexpr int BB = 2, TT = 2048, CC = 1024, HH = 16, DD = 64;
constexpr int MDIM = BB * TT;  // 4096

DEV u16 f2bf(float f) {
  unsigned int u = __builtin_bit_cast(unsigned int, f);
  u += 0x7fffu + ((u >> 16) & 1u);
  return (u16)(u >> 16);
}
DEV float bf2f(u16 h) {
  unsigned int u = ((unsigned int)h) << 16;
  return __builtin_bit_cast(float, u);
}
DEV void async16(const void* g, void* l) {
  __builtin_amdgcn_global_load_lds(
      (const __attribute__((address_space(1))) unsigned int*)g,
      (__attribute__((address_space(3))) unsigned int*)l, 16, 0, 0);
}
DEV void mfma16(f32x4& acc, u32x4 a, u32x4 b) {
  asm volatile("v_mfma_f32_16x16x32_bf16 %0, %1, %2, %0"
               : "+v"(acc)
               : "v"(a), "v"(b));
}
DEV void mfma32(f32x16& acc, u32x4 a, u32x4 b) {
  asm volatile("v_mfma_f32_32x32x16_bf16 %0, %1, %2, %0"
               : "+v"(acc)
               : "v"(a), "v"(b));
}
DEV u32 cvtpk(float lo, float hi) {
  u32 r;
  asm("v_cvt_pk_bf16_f32 %0, %1, %2" : "=v"(r) : "v"(lo), "v"(hi));
  return r;
}
DEV void pswap(u32& a, u32& b) {
#if __has_builtin(__builtin_amdgcn_permlane32_swap)
  u32x2 r = __builtin_amdgcn_permlane32_swap(a, b, false, false);
  a = r.x;
  b = r.y;
#else
  asm volatile("v_permlane32_swap_b32 %0, %1" : "+v"(a), "+v"(b));
#endif
}
DEV float exp2g(float x) {
#if __has_builtin(__builtin_amdgcn_exp2f)
  return __builtin_amdgcn_exp2f(x);
#else
  return exp2f(x);
#endif
}

// ---------------------------------------------------------------- prep ----
// One launch: W_attn transpose (bx<96), W_proj transpose (96<=bx<128),
// x f32->bf16 convert (bx>=128; 1024 blocks x 1024 thr x 4 elems).
__global__ void prep_all(const float* __restrict__ x,
                         const float* __restrict__ Wa, const float* __restrict__ Wp,
                         u16* __restrict__ x_bf,
                         u16* __restrict__ Wa_t, u16* __restrict__ Wp_t) {
  __shared__ float tile[32][33];
  int bx = blockIdx.x;
  const int tx = threadIdx.x, ty = threadIdx.y;
  if (bx >= 128) {
    const int cb = (bx - 128) * 32 + blockIdx.y;
    const int i = (cb * 1024 + ty * 32 + tx) * 4;
    f32x4 v = *(const f32x4*)(x + i);
    u16x4 o;
#pragma unroll
    for (int j = 0; j < 4; ++j) o[j] = f2bf(v[j]);
    *(u16x4*)(x_bf + i) = o;
    return;
  }
  const float* in;
  u16* out;
  int Cc;
  if (bx < 96) { in = Wa; out = Wa_t; Cc = 3072; }
  else { bx -= 96; in = Wp; out = Wp_t; Cc = 1024; }
  const int R = 1024;
  const int x0 = bx * 32, y0 = blockIdx.y * 32;
  tile[ty][tx] = in[(size_t)(y0 + ty) * Cc + (x0 + tx)];
  __syncthreads();
  out[(size_t)(x0 + ty) * R + (y0 + tx)] = f2bf(tile[tx][ty]);
}

// ---------------------------------------------------------------- GEMM ----
// R5/R9-proven: m97 structure (128x128, BK=64, 4 waves, single-buffer LDS)
// + bijective XCD patch swizzle + LDS-coalesced epilogues.
template <int MODE>
__global__ __launch_bounds__(256) void gemm_bf16(
    const u16* __restrict__ A, const u16* __restrict__ Bt,
    const float* __restrict__ bias, float* __restrict__ outF,
    u16* __restrict__ qw, u16* __restrict__ kw, u16* __restrict__ vw,
    int M, int N, int K) {
  __shared__ alignas(16) u16 Sh[2][128 * 64];
  u16* Asp = Sh[0];
  u16* Bsp = Sh[1];
  const int tid = threadIdx.x;
  const int lane = tid & 63, w = tid >> 6;
  const int g = lane >> 4, c16 = lane & 15;
  const int wm = (w >> 1) * 64, wn = (w & 1) * 64;

  const int wgid = blockIdx.y * gridDim.x + blockIdx.x;
  const int xcd = wgid & 7, pi = wgid >> 3;
  int bxs, bys;
  if (MODE == 1) {  // 24 x 32
    bxs = 12 * (xcd & 1) + pi % 12;
    bys = 8 * (xcd >> 1) + pi / 12;
  } else {          // 8 x 32
    bxs = pi & 7;
    bys = 4 * xcd + (pi >> 3);
  }
  const int brow = bys * 128, bcol = bxs * 128;

  const int lrow = lane >> 3;
  const int scol = ((lane & 7) ^ lrow) << 4;
  const int rswz = (c16 & 7) << 4;

  f32x4 acc[4][4];
#pragma unroll
  for (int m = 0; m < 4; ++m)
#pragma unroll
    for (int n = 0; n < 4; ++n) acc[m][n] = f32x4{0.f, 0.f, 0.f, 0.f};

  const size_t ldb = (size_t)K * 2;
  const char* Abase = (const char*)A + (size_t)brow * ldb;
  const char* Bbase = (const char*)Bt + (size_t)bcol * ldb;

  for (int kt = 0; kt < K; kt += 64) {
    __syncthreads();
#pragma unroll
    for (int i = 0; i < 4; ++i) {
      const int chunk = i * 4 + w;
      const int row = chunk * 8 + lrow;
      async16(Abase + (size_t)row * ldb + (size_t)kt * 2 + scol, (char*)Asp + chunk * 1024);
      async16(Bbase + (size_t)row * ldb + (size_t)kt * 2 + scol, (char*)Bsp + chunk * 1024);
    }
    __syncthreads();
#pragma unroll
    for (int kc = 0; kc < 2; ++kc) {
      const int cb = (kc * 64 + g * 16) ^ rswz;
      u32x4 af[4], bf8[4];
#pragma unroll
      for (int m = 0; m < 4; ++m)
        af[m] = *(const u32x4*)((const char*)Asp + (wm + m * 16 + c16) * 128 + cb);
#pragma unroll
      for (int n = 0; n < 4; ++n)
        bf8[n] = *(const u32x4*)((const char*)Bsp + (wn + n * 16 + c16) * 128 + cb);
#pragma unroll
      for (int m = 0; m < 4; ++m)
#pragma unroll
        for (int n = 0; n < 4; ++n) mfma16(acc[m][n], af[m], bf8[n]);
    }
  }

  if (MODE == 0) {
    float* Ef = (float*)&Sh[0][0];  // [64][128] f32
#pragma unroll
    for (int pass = 0; pass < 2; ++pass) {
      __syncthreads();
      if ((wm >> 6) == pass) {
#pragma unroll
        for (int n = 0; n < 4; ++n) {
          const float bv = bias[bcol + wn + n * 16 + c16];
#pragma unroll
          for (int m = 0; m < 4; ++m)
#pragma unroll
            for (int r = 0; r < 4; ++r)
              Ef[(m * 16 + g * 4 + r) * 128 + wn + n * 16 + c16] = acc[m][n][r] + bv;
        }
      }
      __syncthreads();
#pragma unroll
      for (int i = 0; i < 8; ++i) {
        const int chunk = tid + i * 256;
        const int row = chunk >> 5;
        const int c4 = (chunk & 31) * 4;
        f32x4 v4 = *(const f32x4*)&Ef[row * 128 + c4];
        *(f32x4*)&outF[(size_t)(brow + pass * 64 + row) * N + bcol + c4] = v4;
      }
    }
  } else {
    u16* E = &Sh[0][0];  // 32KB = [128][128] u16
    const int which = bcol >> 10;
    __syncthreads();
    if (which < 2) {
#pragma unroll
      for (int n = 0; n < 4; ++n) {
        const float bv = bias[bcol + wn + n * 16 + c16];
#pragma unroll
        for (int m = 0; m < 4; ++m)
#pragma unroll
          for (int r = 0; r < 4; ++r)
            E[(wm + m * 16 + g * 4 + r) * 128 + wn + n * 16 + c16] =
                f2bf(acc[m][n][r] + bv);
      }
    } else {  // v: stage transposed so t becomes contiguous
#pragma unroll
      for (int n = 0; n < 4; ++n) {
        const float bv = bias[bcol + wn + n * 16 + c16];
#pragma unroll
        for (int m = 0; m < 4; ++m) {
          u16x4 t4;
#pragma unroll
          for (int r = 0; r < 4; ++r) t4[r] = f2bf(acc[m][n][r] + bv);
          *(u16x4*)&E[(wn + n * 16 + c16) * 128 + wm + m * 16 + g * 4] = t4;
        }
      }
    }
    __syncthreads();
#pragma unroll
    for (int i = 0; i < 8; ++i) {
      const int chunk = tid + i * 256;
      if (which < 2) {
        const int row = chunk >> 4;
        const int cc8 = (chunk & 15) * 8;
        const int colg = bcol + cc8;
        const int c = colg & 1023, h = c >> 6, d = c & 63;
        const int rowg = brow + row, b = rowg >> 11, t = rowg & (TT - 1);
        u16x8 v8 = *(const u16x8*)&E[row * 128 + cc8];
        u16* dst = (which == 0 ? qw : kw) + ((size_t)(b * HH + h) * TT + t) * DD + d;
        *(u16x8*)dst = v8;
      } else {
        const int drow = chunk >> 4;
        const int t8 = (chunk & 15) * 8;
        const int colg = bcol + drow;
        const int c = colg & 1023, h = c >> 6, d = c & 63;
        const int rowg = brow + t8, b = rowg >> 11, t = rowg & (TT - 1);
        u16x8 v8 = *(const u16x8*)&E[drow * 128 + t8];
        u16* dst = vw + ((size_t)(b * HH + h) * DD + d) * TT + t;
        *(u16x8*)dst = v8;
      }
    }
  }
}

// ----------------------------------------------------------- attention ----
// R10: KVBLK 64->32 so LDS = 32KB -> 4 blocks/CU (2x wave budget; we are
// latency-bound at ~12% occupancy). 4-deep K[32][64sw] + V[64][32sw] buffers,
// stage distance 3, in-loop vmcnt(2) (stage t+1 landed for ahead-QK; t+2 in
// flight). Fixed-base softmax (R9), QK(t+1)-ahead pipeline (R8).
// V 64B rows: 2-bit XOR swizzle (slot ^= (row>>1)&3; source pre-swizzled,
// rule #21) -> ~4-way conflicts instead of 16-way.
__global__ __launch_bounds__(256) void attn_fwd(
    const u16* __restrict__ qw, const u16* __restrict__ kw,
    const u16* __restrict__ vw, u16* __restrict__ ao) {
  extern __shared__ u16 smem[];  // K: 4 x 4KB | V: 4 x 4KB = 32KB
  const int tid = threadIdx.x;
  const int lane = tid & 63, w = tid >> 6;  // 4 waves
  const int ql = lane & 31, half = lane >> 5;
  const int bh = blockIdx.y;
  const int qb = ((bh >> 4) & 1) ? (15 - blockIdx.x) : blockIdx.x;  // pairing
  const int q0w = qb * 128 + w * 32;
  const int qg = q0w + ql;
  const int lrow = lane >> 3;
  const int scol = ((lane & 7) ^ lrow) << 4;       // K source pre-swizzle
  const int rswz = (ql & 7) << 4;                  // K read swizzle
  const int vsrc = ((lane & 3) ^ ((lane >> 3) & 3)) << 4;  // V source pre-swz
  const int vrswz = ((ql >> 1) & 3) << 4;          // V read swizzle

  u32x4 qf[4];
  {
    const u16* qrow = qw + ((size_t)bh * TT + qg) * DD;
    const float qs = 0.125f * 1.44269504f;  // fold 1/sqrt(D) * log2(e)
#pragma unroll
    for (int dwin = 0; dwin < 4; ++dwin) {
      u16x8 u = *(const u16x8*)(qrow + dwin * 16 + half * 8);
      u16x8 s;
#pragma unroll
      for (int j = 0; j < 8; ++j) s[j] = f2bf(bf2f(u[j]) * qs);
      qf[dwin] = __builtin_bit_cast(u32x4, s);
    }
  }

  f32x16 o0, o1;
#pragma unroll
  for (int i = 0; i < 16; ++i) { o0[i] = 0.f; o1[i] = 0.f; }
  float l_run = 0.f;

  const char* kbase = (const char*)kw + ((size_t)bh * TT) * 128;       // 128B rows
  const char* vbase = (const char*)vw + ((size_t)bh * DD) * (TT * 2);  // 4096B rows

  const int nt = 4 * (qb + 1);  // 32-key tiles; >=4, divisible by 2

  auto kptr = [&](int b) { return (char*)smem + b * 4096; };
  auto vptr = [&](int b) { return (char*)smem + 16384 + b * 4096; };

  // per wave: 1 K chunk (rows w*8..w*8+7 of 32) + 1 V chunk (d 16w..16w+15)
  auto STAGE = [&](int kt_) {
    if (kt_ >= nt) return;
    const int buf = kt_ & 3;
    const int t0_ = kt_ * 32;
    const int krow = w * 8 + lrow;
    async16(kbase + (size_t)(t0_ + krow) * 128 + scol, kptr(buf) + w * 1024);
    const int vrow = w * 16 + (lane >> 2);
    async16(vbase + (size_t)vrow * (TT * 2) + (size_t)t0_ * 2 + vsrc,
            vptr(buf) + w * 1024);
  };

  // S^T = K(32k x 64d) * Q^T: lane q=ql, k = (r&3)+8*(r>>2)+4*half
  auto QK = [&](int kt_, f32x16& sa) {
    const char* Kc = kptr(kt_ & 3);
#pragma unroll
    for (int i = 0; i < 16; ++i) sa[i] = 0.f;
    __builtin_amdgcn_s_setprio(1);
#pragma unroll
    for (int dwin = 0; dwin < 4; ++dwin) {
      const int cb = (dwin * 32 + half * 16) ^ rswz;
      u32x4 ak = *(const u32x4*)(Kc + ql * 128 + cb);
      mfma32(sa, ak, qf[dwin]);
    }
    __builtin_amdgcn_s_setprio(0);
  };

  // mask + fixed-base softmax + PV for 32-key tile kt
  auto FINISH = [&](int kt_, f32x16& s) {
    const int t0 = kt_ * 32;
    if (t0 >= q0w + 32) return;  // wave-uniform skip
    if (t0 + 31 > q0w) {         // causal mask, register-local
      const int kb = t0 + 4 * half - qg;
#pragma unroll
      for (int r = 0; r < 16; ++r) {
        const int ko = (r & 3) + 8 * (r >> 2);
        if (kb + ko > 0) s[r] = -1e30f;
      }
    }
#pragma unroll
    for (int i = 0; i < 16; ++i) s[i] = exp2g(s[i]);
    float a4[4];
#pragma unroll
    for (int i = 0; i < 4; ++i)
      a4[i] = (s[i] + s[i + 4]) + (s[i + 8] + s[i + 12]);
    float rs = (a4[0] + a4[1]) + (a4[2] + a4[3]);
    rs += __shfl_xor(rs, 32, 64);
    l_run += rs;

    u32x4 pf[2];
#pragma unroll
    for (int win = 0; win < 2; ++win) {
      const int b = win * 8;
      u32 w0 = cvtpk(s[b + 0], s[b + 1]), w2 = cvtpk(s[b + 4], s[b + 5]);
      u32 w1 = cvtpk(s[b + 2], s[b + 3]), w3 = cvtpk(s[b + 6], s[b + 7]);
      pswap(w0, w2);
      pswap(w1, w3);
      pf[win] = u32x4{w0, w1, w2, w3};
    }
    const char* Vc = vptr(kt_ & 3);
    __builtin_amdgcn_s_setprio(1);
#pragma unroll
    for (int win = 0; win < 2; ++win) {
      const int cb = (win * 32 + half * 16) ^ vrswz;
      u32x4 av0 = *(const u32x4*)(Vc + (0 + ql) * 64 + cb);
      u32x4 av1 = *(const u32x4*)(Vc + (32 + ql) * 64 + cb);
      mfma32(o0, av0, pf[win]);
      mfma32(o1, av1, pf[win]);
    }
    __builtin_amdgcn_s_setprio(0);
  };

  STAGE(0);
  STAGE(1);
  STAGE(2);
  asm volatile("s_waitcnt vmcnt(4)" ::: "memory");  // stage(0) landed
  __builtin_amdgcn_sched_barrier(0);
  __builtin_amdgcn_s_barrier();
  __builtin_amdgcn_sched_barrier(0);

  f32x16 sA, sB;
  QK(0, sA);

#define BODY(KT, C, N)                                                    \
  {                                                                       \
    const int kt_b = (KT);                                                \
    if (kt_b + 2 < nt)                                                    \
      asm volatile("s_waitcnt vmcnt(2)" ::: "memory");                    \
    else                                                                  \
      asm volatile("s_waitcnt vmcnt(0)" ::: "memory");                    \
    __builtin_amdgcn_sched_barrier(0);                                    \
    __builtin_amdgcn_s_barrier();                                         \
    __builtin_amdgcn_sched_barrier(0);                                    \
    STAGE(kt_b + 3);                                                      \
    if (kt_b + 1 < nt && (kt_b + 1) * 32 < q0w + 32) QK(kt_b + 1, N);     \
    FINISH(kt_b, C);                                                      \
  }

  for (int kt2 = 0; kt2 < nt; kt2 += 2) {
    BODY(kt2, sA, sB);
    BODY(kt2 + 1, sB, sA);
  }
#undef BODY

  // epilogue: lane holds O^T[d][qg]; d = sub*32 + 8*rg + 4*half + j
  const int b = bh >> 4, h = bh & 15;
  const float inv = 1.f / l_run;
  u16* aorow = ao + ((size_t)(b * TT) + qg) * CC + h * DD;
#pragma unroll
  for (int rg = 0; rg < 4; ++rg) {
    u16x4 t0v, t1v;
#pragma unroll
    for (int j = 0; j < 4; ++j) {
      t0v[j] = f2bf(o0[rg * 4 + j] * inv);
      t1v[j] = f2bf(o1[rg * 4 + j] * inv);
    }
    *(u16x4*)(aorow + 8 * rg + 4 * half) = t0v;
    *(u16x4*)(aorow + 32 + 8 * rg + 4 * half) = t1v;
  }
}

// -------------------------------------------------------------- launch ----
extern "C" void kernel_launch(void* const* d_in, const int* in_sizes, int n_in,
                              void* d_out, int out_size, void* d_ws, size_t ws_size,
                              hipStream_t stream) {
  const float* x  = (const float*)d_in[0];
  const float* Wa = (const float*)d_in[1];
  const float* ba = (const float*)d_in[2];
  const float* Wp = (const float*)d_in[3];
  const float* bp = (const float*)d_in[4];
  float* out = (float*)d_out;

  char* ws = (char*)d_ws;
  const size_t MB = 1ull << 20;
  u16* x_bf = (u16*)(ws);            // 8 MB  [4096][1024]
  u16* ao   = (u16*)(ws);            // 8 MB  alias (x_bf dead after QKV GEMM)
  u16* Wa_t = (u16*)(ws + 8 * MB);   // 6 MB  [3072][1024]
  u16* Wp_t = (u16*)(ws + 14 * MB);  // 2 MB  [1024][1024]
  u16* q_ws = (u16*)(ws + 16 * MB);  // 8 MB  [32][2048][64]
  u16* k_ws = (u16*)(ws + 24 * MB);  // 8 MB  [32][2048][64]
  u16* v_ws = (u16*)(ws + 32 * MB);  // 8 MB  [32][64][2048]

  hipLaunchKernelGGL(prep_all, dim3(160, 32), dim3(32, 32), 0, stream,
                     x, Wa, Wp, x_bf, Wa_t, Wp_t);
  hipLaunchKernelGGL((gemm_bf16<1>), dim3(3 * CC / 128, MDIM / 128), dim3(256), 0, stream,
                     x_bf, Wa_t, ba, nullptr, q_ws, k_ws, v_ws, MDIM, 3 * CC, CC);
  hipLaunchKernelGGL(attn_fwd, dim3(TT / 128, BB * HH), dim3(256), 32768, stream,
                     q_ws, k_ws, v_ws, ao);
  hipLaunchKernelGGL((gemm_bf16<0>), dim3(CC / 128, MDIM / 128), dim3(256), 0, stream,
                     ao, Wp_t, bp, out, nullptr, nullptr, nullptr, MDIM, CC, CC);
}

// Round 12
// 117.221 us; speedup vs baseline: 1.0017x; 1.0017x over previous
//
#include <hip/hip_runtime.h>

typedef unsigned short u16;
typedef unsigned int u32;
typedef float f32x4 __attribute__((ext_vector_type(4)));
typedef float f32x16 __attribute__((ext_vector_type(16)));
typedef unsigned int u32x4 __attribute__((ext_vector_type(4)));
typedef unsigned int u32x2 __attribute__((ext_vector_type(2)));
typedef unsigned short u16x8 __attribute__((ext_vector_type(8)));
typedef unsigned short u16x4 __attribute__((ext_vector_type(4)));

#define DEV static __device__ __forceinline__

constexpr int BB = 2, TT = 2048, CC = 1024, HH = 16, DD = 64;
constexpr int MDIM = BB * TT;  // 4096

DEV u16 f2bf(float f) {
  unsigned int u = __builtin_bit_cast(unsigned int, f);
  u += 0x7fffu + ((u >> 16) & 1u);
  return (u16)(u >> 16);
}
DEV float bf2f(u16 h) {
  unsigned int u = ((unsigned int)h) << 16;
  return __builtin_bit_cast(float, u);
}
DEV void async16(const void* g, void* l) {
  __builtin_amdgcn_global_load_lds(
      (const __attribute__((address_space(1))) unsigned int*)g,
      (__attribute__((address_space(3))) unsigned int*)l, 16, 0, 0);
}
DEV void mfma16(f32x4& acc, u32x4 a, u32x4 b) {
  asm volatile("v_mfma_f32_16x16x32_bf16 %0, %1, %2, %0"
               : "+v"(acc)
               : "v"(a), "v"(b));
}
DEV void mfma32(f32x16& acc, u32x4 a, u32x4 b) {
  asm volatile("v_mfma_f32_32x32x16_bf16 %0, %1, %2, %0"
               : "+v"(acc)
               : "v"(a), "v"(b));
}
DEV u32 cvtpk(float lo, float hi) {
  u32 r;
  asm("v_cvt_pk_bf16_f32 %0, %1, %2" : "=v"(r) : "v"(lo), "v"(hi));
  return r;
}
DEV void pswap(u32& a, u32& b) {
#if __has_builtin(__builtin_amdgcn_permlane32_swap)
  u32x2 r = __builtin_amdgcn_permlane32_swap(a, b, false, false);
  a = r.x;
  b = r.y;
#else
  asm volatile("v_permlane32_swap_b32 %0, %1" : "+v"(a), "+v"(b));
#endif
}
DEV float exp2g(float x) {
#if __has_builtin(__builtin_amdgcn_exp2f)
  return __builtin_amdgcn_exp2f(x);
#else
  return exp2f(x);
#endif
}

// ---------------------------------------------------------------- prep ----
// One launch: W_attn transpose (bx<96), W_proj transpose (96<=bx<128),
// x f32->bf16 convert (bx>=128).
__global__ void prep_all(const float* __restrict__ x,
                         const float* __restrict__ Wa, const float* __restrict__ Wp,
                         u16* __restrict__ x_bf,
                         u16* __restrict__ Wa_t, u16* __restrict__ Wp_t) {
  __shared__ float tile[32][33];
  int bx = blockIdx.x;
  const int tx = threadIdx.x, ty = threadIdx.y;
  if (bx >= 128) {
    const int cb = (bx - 128) * 32 + blockIdx.y;
    const int i = (cb * 1024 + ty * 32 + tx) * 4;
    f32x4 v = *(const f32x4*)(x + i);
    u16x4 o;
#pragma unroll
    for (int j = 0; j < 4; ++j) o[j] = f2bf(v[j]);
    *(u16x4*)(x_bf + i) = o;
    return;
  }
  const float* in;
  u16* out;
  int Cc;
  if (bx < 96) { in = Wa; out = Wa_t; Cc = 3072; }
  else { bx -= 96; in = Wp; out = Wp_t; Cc = 1024; }
  const int R = 1024;
  const int x0 = bx * 32, y0 = blockIdx.y * 32;
  tile[ty][tx] = in[(size_t)(y0 + ty) * Cc + (x0 + tx)];
  __syncthreads();
  out[(size_t)(x0 + ty) * R + (y0 + tx)] = f2bf(tile[tx][ty]);
}

// ---------------------------------------------------------------- GEMM ----
// R5/R9-proven: m97 structure (128x128, BK=64, 4 waves, single-buffer LDS)
// + bijective XCD patch swizzle + LDS-coalesced epilogues.
template <int MODE>
__global__ __launch_bounds__(256) void gemm_bf16(
    const u16* __restrict__ A, const u16* __restrict__ Bt,
    const float* __restrict__ bias, float* __restrict__ outF,
    u16* __restrict__ qw, u16* __restrict__ kw, u16* __restrict__ vw,
    int M, int N, int K) {
  __shared__ alignas(16) u16 Sh[2][128 * 64];
  u16* Asp = Sh[0];
  u16* Bsp = Sh[1];
  const int tid = threadIdx.x;
  const int lane = tid & 63, w = tid >> 6;
  const int g = lane >> 4, c16 = lane & 15;
  const int wm = (w >> 1) * 64, wn = (w & 1) * 64;

  const int wgid = blockIdx.y * gridDim.x + blockIdx.x;
  const int xcd = wgid & 7, pi = wgid >> 3;
  int bxs, bys;
  if (MODE == 1) {  // 24 x 32
    bxs = 12 * (xcd & 1) + pi % 12;
    bys = 8 * (xcd >> 1) + pi / 12;
  } else {          // 8 x 32
    bxs = pi & 7;
    bys = 4 * xcd + (pi >> 3);
  }
  const int brow = bys * 128, bcol = bxs * 128;

  const int lrow = lane >> 3;
  const int scol = ((lane & 7) ^ lrow) << 4;
  const int rswz = (c16 & 7) << 4;

  f32x4 acc[4][4];
#pragma unroll
  for (int m = 0; m < 4; ++m)
#pragma unroll
    for (int n = 0; n < 4; ++n) acc[m][n] = f32x4{0.f, 0.f, 0.f, 0.f};

  const size_t ldb = (size_t)K * 2;
  const char* Abase = (const char*)A + (size_t)brow * ldb;
  const char* Bbase = (const char*)Bt + (size_t)bcol * ldb;

  for (int kt = 0; kt < K; kt += 64) {
    __syncthreads();
#pragma unroll
    for (int i = 0; i < 4; ++i) {
      const int chunk = i * 4 + w;
      const int row = chunk * 8 + lrow;
      async16(Abase + (size_t)row * ldb + (size_t)kt * 2 + scol, (char*)Asp + chunk * 1024);
      async16(Bbase + (size_t)row * ldb + (size_t)kt * 2 + scol, (char*)Bsp + chunk * 1024);
    }
    __syncthreads();
#pragma unroll
    for (int kc = 0; kc < 2; ++kc) {
      const int cb = (kc * 64 + g * 16) ^ rswz;
      u32x4 af[4], bf8[4];
#pragma unroll
      for (int m = 0; m < 4; ++m)
        af[m] = *(const u32x4*)((const char*)Asp + (wm + m * 16 + c16) * 128 + cb);
#pragma unroll
      for (int n = 0; n < 4; ++n)
        bf8[n] = *(const u32x4*)((const char*)Bsp + (wn + n * 16 + c16) * 128 + cb);
#pragma unroll
      for (int m = 0; m < 4; ++m)
#pragma unroll
        for (int n = 0; n < 4; ++n) mfma16(acc[m][n], af[m], bf8[n]);
    }
  }

  if (MODE == 0) {
    float* Ef = (float*)&Sh[0][0];  // [64][128] f32
#pragma unroll
    for (int pass = 0; pass < 2; ++pass) {
      __syncthreads();
      if ((wm >> 6) == pass) {
#pragma unroll
        for (int n = 0; n < 4; ++n) {
          const float bv = bias[bcol + wn + n * 16 + c16];
#pragma unroll
          for (int m = 0; m < 4; ++m)
#pragma unroll
            for (int r = 0; r < 4; ++r)
              Ef[(m * 16 + g * 4 + r) * 128 + wn + n * 16 + c16] = acc[m][n][r] + bv;
        }
      }
      __syncthreads();
#pragma unroll
      for (int i = 0; i < 8; ++i) {
        const int chunk = tid + i * 256;
        const int row = chunk >> 5;
        const int c4 = (chunk & 31) * 4;
        f32x4 v4 = *(const f32x4*)&Ef[row * 128 + c4];
        *(f32x4*)&outF[(size_t)(brow + pass * 64 + row) * N + bcol + c4] = v4;
      }
    }
  } else {
    u16* E = &Sh[0][0];  // 32KB = [128][128] u16
    const int which = bcol >> 10;
    __syncthreads();
    if (which < 2) {
#pragma unroll
      for (int n = 0; n < 4; ++n) {
        const float bv = bias[bcol + wn + n * 16 + c16];
#pragma unroll
        for (int m = 0; m < 4; ++m)
#pragma unroll
          for (int r = 0; r < 4; ++r)
            E[(wm + m * 16 + g * 4 + r) * 128 + wn + n * 16 + c16] =
                f2bf(acc[m][n][r] + bv);
      }
    } else {  // v: stage transposed so t becomes contiguous
#pragma unroll
      for (int n = 0; n < 4; ++n) {
        const float bv = bias[bcol + wn + n * 16 + c16];
#pragma unroll
        for (int m = 0; m < 4; ++m) {
          u16x4 t4;
#pragma unroll
          for (int r = 0; r < 4; ++r) t4[r] = f2bf(acc[m][n][r] + bv);
          *(u16x4*)&E[(wn + n * 16 + c16) * 128 + wm + m * 16 + g * 4] = t4;
        }
      }
    }
    __syncthreads();
#pragma unroll
    for (int i = 0; i < 8; ++i) {
      const int chunk = tid + i * 256;
      if (which < 2) {
        const int row = chunk >> 4;
        const int cc8 = (chunk & 15) * 8;
        const int colg = bcol + cc8;
        const int c = colg & 1023, h = c >> 6, d = c & 63;
        const int rowg = brow + row, b = rowg >> 11, t = rowg & (TT - 1);
        u16x8 v8 = *(const u16x8*)&E[row * 128 + cc8];
        u16* dst = (which == 0 ? qw : kw) + ((size_t)(b * HH + h) * TT + t) * DD + d;
        *(u16x8*)dst = v8;
      } else {
        const int drow = chunk >> 4;
        const int t8 = (chunk & 15) * 8;
        const int colg = bcol + drow;
        const int c = colg & 1023, h = c >> 6, d = c & 63;
        const int rowg = brow + t8, b = rowg >> 11, t = rowg & (TT - 1);
        u16x8 v8 = *(const u16x8*)&E[drow * 128 + t8];
        u16* dst = vw + ((size_t)(b * HH + h) * DD + d) * TT + t;
        *(u16x8*)dst = v8;
      }
    }
  }
}

// ----------------------------------------------------------- attention ----
// R9 structure (KVBLK=64, 4-deep LDS, counted vmcnt, QK(t+1)-ahead pipeline,
// fixed-base softmax) + R11 split-K over key tiles for qb>=8 (fixed-base
// partials are additive: O = sum O_s, l = sum l_s). Grid 24 x 32:
//   bx<8          : qb=bx, full tile range, normalized write to ao.
//   bx>=8 (i=bx-8): qb=8+(i>>1), split s=i&1, tiles [s*(qb+1), (s+1)*(qb+1));
//     s=0 writes UNNORMALIZED bf16 O into ao slot + l0; s=1 into O1 + l1.
// Every block is now <=16 tile-units (was <=32) -> tail halves.
__global__ __launch_bounds__(256) void attn_fwd(
    const u16* __restrict__ qw, const u16* __restrict__ kw,
    const u16* __restrict__ vw, u16* __restrict__ ao,
    u16* __restrict__ O1, float* __restrict__ lpart) {
  extern __shared__ u16 smem[];  // [4][64*64] K, then [4][64*64] V  (64KB)
  const int tid = threadIdx.x;
  const int lane = tid & 63, w = tid >> 6;  // 4 waves
  const int ql = lane & 31, half = lane >> 5;
  const int bh = blockIdx.y;
  int bx = blockIdx.x;            // 0..23
  if (bh & 1) bx = 23 - bx;       // mix block order across bh
  int qb, t_begin, cnt, sp;       // sp: -1 normal, 0/1 split half
  if (bx < 8) {
    qb = bx; sp = -1; t_begin = 0; cnt = 2 * qb + 2;
  } else {
    const int i = bx - 8;
    qb = 8 + (i >> 1); sp = i & 1; cnt = qb + 1; t_begin = sp * cnt;
  }
  const int t_end = t_begin + cnt;

  const int q0w = qb * 128 + w * 32;
  const int qg = q0w + ql;
  const int lrow = lane >> 3;
  const int scol = ((lane & 7) ^ lrow) << 4;
  const int rswz = (ql & 7) << 4;

  u32x4 qf[4];
  {
    const u16* qrow = qw + ((size_t)bh * TT + qg) * DD;
    const float qs = 0.125f * 1.44269504f;  // fold 1/sqrt(D) * log2(e)
#pragma unroll
    for (int dwin = 0; dwin < 4; ++dwin) {
      u16x8 u = *(const u16x8*)(qrow + dwin * 16 + half * 8);
      u16x8 s;
#pragma unroll
      for (int j = 0; j < 8; ++j) s[j] = f2bf(bf2f(u[j]) * qs);
      qf[dwin] = __builtin_bit_cast(u32x4, s);
    }
  }

  f32x16 o0, o1;
#pragma unroll
  for (int i = 0; i < 16; ++i) { o0[i] = 0.f; o1[i] = 0.f; }
  float l_run = 0.f;

  const char* kbase = (const char*)kw + ((size_t)bh * TT) * 128;       // 128B rows
  const char* vbase = (const char*)vw + ((size_t)bh * DD) * (TT * 2);  // 4096B rows

  auto kptr = [&](int b) { return (char*)(smem + (b & 3) * 4096); };
  auto vptr = [&](int b) { return (char*)(smem + 16384 + (b & 3) * 4096); };

  auto STAGE = [&](int kt_) {
    if (kt_ >= t_end) return;
    const int t0_ = kt_ * 64;
#pragma unroll
    for (int i_ = 0; i_ < 2; ++i_) {
      const int chunk = w * 2 + i_;
      const int row = chunk * 8 + lrow;
      async16(kbase + (size_t)(t0_ + row) * 128 + scol, kptr(kt_) + chunk * 1024);
      async16(vbase + (size_t)row * (TT * 2) + (size_t)t0_ * 2 + scol,
              vptr(kt_) + chunk * 1024);
    }
  };

  auto QK = [&](int kt_, f32x16& sa, f32x16& sb) {
    const char* Kc = kptr(kt_);
#pragma unroll
    for (int i = 0; i < 16; ++i) { sa[i] = 0.f; sb[i] = 0.f; }
    __builtin_amdgcn_s_setprio(1);
#pragma unroll
    for (int dwin = 0; dwin < 4; ++dwin) {
      const int cb = (dwin * 32 + half * 16) ^ rswz;
      u32x4 ak0 = *(const u32x4*)(Kc + (0 + ql) * 128 + cb);
      u32x4 ak1 = *(const u32x4*)(Kc + (32 + ql) * 128 + cb);
      mfma32(sa, ak0, qf[dwin]);
      mfma32(sb, ak1, qf[dwin]);
    }
    __builtin_amdgcn_s_setprio(0);
  };

  auto FINISH = [&](int kt_, f32x16& s0, f32x16& s1) {
    const int t0 = kt_ * 64;
    if (t0 >= q0w + 32) return;  // wave-uniform skip of fully-masked tiles
    if (t0 + 63 > q0w) {         // causal mask, register-local
      const int kb = t0 + 4 * half - qg;
#pragma unroll
      for (int r = 0; r < 16; ++r) {
        const int ko = (r & 3) + 8 * (r >> 2);
        if (kb + ko > 0) s0[r] = -1e30f;
        if (kb + 32 + ko > 0) s1[r] = -1e30f;
      }
    }
#pragma unroll
    for (int i = 0; i < 16; ++i) {
      s0[i] = exp2g(s0[i]);
      s1[i] = exp2g(s1[i]);
    }
    float a8[8];
#pragma unroll
    for (int i = 0; i < 8; ++i)
      a8[i] = (s0[i] + s0[i + 8]) + (s1[i] + s1[i + 8]);
    float rs = ((a8[0] + a8[1]) + (a8[2] + a8[3])) + ((a8[4] + a8[5]) + (a8[6] + a8[7]));
    rs += __shfl_xor(rs, 32, 64);
    l_run += rs;

    u32x4 pf[4];
#pragma unroll
    for (int win = 0; win < 4; ++win) {
      const int b = (win & 1) * 8;
      u32 w0, w1, w2, w3;
      if (win < 2) {
        w0 = cvtpk(s0[b + 0], s0[b + 1]); w2 = cvtpk(s0[b + 4], s0[b + 5]);
        w1 = cvtpk(s0[b + 2], s0[b + 3]); w3 = cvtpk(s0[b + 6], s0[b + 7]);
      } else {
        w0 = cvtpk(s1[b + 0], s1[b + 1]); w2 = cvtpk(s1[b + 4], s1[b + 5]);
        w1 = cvtpk(s1[b + 2], s1[b + 3]); w3 = cvtpk(s1[b + 6], s1[b + 7]);
      }
      pswap(w0, w2);
      pswap(w1, w3);
      pf[win] = u32x4{w0, w1, w2, w3};
    }
    const char* Vc = vptr(kt_);
    __builtin_amdgcn_s_setprio(1);
#pragma unroll
    for (int win = 0; win < 4; ++win) {
      const int cb = (win * 32 + half * 16) ^ rswz;
      u32x4 av0 = *(const u32x4*)(Vc + (0 + ql) * 128 + cb);
      u32x4 av1 = *(const u32x4*)(Vc + (32 + ql) * 128 + cb);
      mfma32(o0, av0, pf[win]);
      mfma32(o1, av1, pf[win]);
    }
    __builtin_amdgcn_s_setprio(0);
  };

  STAGE(t_begin);
  if (cnt > 1) STAGE(t_begin + 1);
  if (cnt > 2) STAGE(t_begin + 2);
  if (cnt >= 3)
    asm volatile("s_waitcnt vmcnt(8)" ::: "memory");
  else
    asm volatile("s_waitcnt vmcnt(4)" ::: "memory");
  __builtin_amdgcn_sched_barrier(0);
  __builtin_amdgcn_s_barrier();
  __builtin_amdgcn_sched_barrier(0);

  f32x16 sA0, sA1, sB0, sB1;
  QK(t_begin, sA0, sA1);

#define BODY(KT, C0, C1, N0, N1)                                          \
  {                                                                       \
    const int kt_b = (KT);                                                \
    if (kt_b + 2 < t_end)                                                 \
      asm volatile("s_waitcnt vmcnt(4)" ::: "memory");                    \
    else                                                                  \
      asm volatile("s_waitcnt vmcnt(0)" ::: "memory");                    \
    __builtin_amdgcn_sched_barrier(0);                                    \
    __builtin_amdgcn_s_barrier();                                         \
    __builtin_amdgcn_sched_barrier(0);                                    \
    STAGE(kt_b + 3);                                                      \
    if (kt_b + 1 < t_end && (kt_b + 1) * 64 < q0w + 32) QK(kt_b + 1, N0, N1);\
    FINISH(kt_b, C0, C1);                                                 \
  }

  int j = 0;
  for (; j + 1 < cnt; j += 2) {
    BODY(t_begin + j, sA0, sA1, sB0, sB1);
    BODY(t_begin + j + 1, sB0, sB1, sA0, sA1);
  }
  if (j < cnt) BODY(t_begin + j, sA0, sA1, sB0, sB1);  // odd-cnt tail
#undef BODY

  // epilogue: lane holds O^T[d][qg]; d = dsub*32 + 8*rg + 4*half + j
  const int b = bh >> 4, h = bh & 15;
  if (sp < 0) {
    const float inv = 1.f / l_run;
    u16* aorow = ao + ((size_t)(b * TT) + qg) * CC + h * DD;
#pragma unroll
    for (int rg = 0; rg < 4; ++rg) {
      u16x4 t0v, t1v;
#pragma unroll
      for (int jj = 0; jj < 4; ++jj) {
        t0v[jj] = f2bf(o0[rg * 4 + jj] * inv);
        t1v[jj] = f2bf(o1[rg * 4 + jj] * inv);
      }
      *(u16x4*)(aorow + 8 * rg + 4 * half) = t0v;
      *(u16x4*)(aorow + 32 + 8 * rg + 4 * half) = t1v;
    }
  } else {
    // unnormalized partial: s=0 -> ao slot (stride CC); s=1 -> O1 (stride DD)
    u16* dst;
    int stride;
    if (sp == 0) { dst = ao + ((size_t)(b * TT) + qg) * CC + h * DD; stride = 1; }
    else { dst = O1 + ((size_t)bh * 1024 + (qg - 1024)) * DD; stride = 1; }
    (void)stride;
#pragma unroll
    for (int rg = 0; rg < 4; ++rg) {
      u16x4 t0v, t1v;
#pragma unroll
      for (int jj = 0; jj < 4; ++jj) {
        t0v[jj] = f2bf(o0[rg * 4 + jj]);
        t1v[jj] = f2bf(o1[rg * 4 + jj]);
      }
      *(u16x4*)(dst + 8 * rg + 4 * half) = t0v;
      *(u16x4*)(dst + 32 + 8 * rg + 4 * half) = t1v;
    }
    if (half == 0) lpart[(size_t)sp * 32768 + bh * 1024 + (qg - 1024)] = l_run;
  }
}

// combine partials for q rows [1024,2048): ao = (ao + O1) / (l0 + l1)
__global__ __launch_bounds__(256) void combine(
    const u16* __restrict__ O1, const float* __restrict__ lpart,
    u16* __restrict__ ao) {
  const int gid = blockIdx.x * 256 + threadIdx.x;  // 262144 threads
  const int d8 = gid & 7;
  const int qq = (gid >> 3) & 1023;
  const int bh = gid >> 13;
  const int b = bh >> 4, h = bh & 15;
  const float l = lpart[bh * 1024 + qq] + lpart[32768 + bh * 1024 + qq];
  const float inv = 1.f / l;
  u16* pa = ao + ((size_t)(b * TT + 1024 + qq)) * CC + h * DD + d8 * 8;
  const u16* p1 = O1 + ((size_t)bh * 1024 + qq) * DD + d8 * 8;
  u16x8 a = *(const u16x8*)pa;
  u16x8 c = *(const u16x8*)p1;
  u16x8 o;
#pragma unroll
  for (int jj = 0; jj < 8; ++jj) o[jj] = f2bf((bf2f(a[jj]) + bf2f(c[jj])) * inv);
  *(u16x8*)pa = o;
}

// -------------------------------------------------------------- launch ----
extern "C" void kernel_launch(void* const* d_in, const int* in_sizes, int n_in,
                              void* d_out, int out_size, void* d_ws, size_t ws_size,
                              hipStream_t stream) {
  const float* x  = (const float*)d_in[0];
  const float* Wa = (const float*)d_in[1];
  const float* ba = (const float*)d_in[2];
  const float* Wp = (const float*)d_in[3];
  const float* bp = (const float*)d_in[4];
  float* out = (float*)d_out;

  char* ws = (char*)d_ws;
  const size_t MB = 1ull << 20;
  u16* x_bf = (u16*)(ws);            // 8 MB  [4096][1024]
  u16* ao   = (u16*)(ws);            // 8 MB  alias (x_bf dead after QKV GEMM)
  u16* Wa_t = (u16*)(ws + 8 * MB);   // 6 MB  [3072][1024] (dead after qkv GEMM)
  u16* O1   = (u16*)(ws + 8 * MB);   // 4 MB  [32][1024][64] (overlays Wa_t)
  float* lp = (float*)(ws + 12 * MB);  // 256KB [2][32][1024] (overlays Wa_t)
  u16* Wp_t = (u16*)(ws + 14 * MB);  // 2 MB  [1024][1024]
  u16* q_ws = (u16*)(ws + 16 * MB);  // 8 MB  [32][2048][64]
  u16* k_ws = (u16*)(ws + 24 * MB);  // 8 MB  [32][2048][64]
  u16* v_ws = (u16*)(ws + 32 * MB);  // 8 MB  [32][64][2048]

  hipLaunchKernelGGL(prep_all, dim3(160, 32), dim3(32, 32), 0, stream,
                     x, Wa, Wp, x_bf, Wa_t, Wp_t);
  hipLaunchKernelGGL((gemm_bf16<1>), dim3(3 * CC / 128, MDIM / 128), dim3(256), 0, stream,
                     x_bf, Wa_t, ba, nullptr, q_ws, k_ws, v_ws, MDIM, 3 * CC, CC);
  hipLaunchKernelGGL(attn_fwd, dim3(24, BB * HH), dim3(256), 65536, stream,
                     q_ws, k_ws, v_ws, ao, O1, lp);
  hipLaunchKernelGGL(combine, dim3(1024), dim3(256), 0, stream, O1, lp, ao);
  hipLaunchKernelGGL((gemm_bf16<0>), dim3(CC / 128, MDIM / 128), dim3(256), 0, stream,
                     ao, Wp_t, bp, out, nullptr, nullptr, nullptr, MDIM, CC, CC);
}

// Round 13
// 110.670 us; speedup vs baseline: 1.0610x; 1.0592x over previous
//
#include <hip/hip_runtime.h>

typedef unsigned short u16;
typedef unsigned int u32;
typedef float f32x4 __attribute__((ext_vector_type(4)));
typedef float f32x16 __attribute__((ext_vector_type(16)));
typedef unsigned int u32x4 __attribute__((ext_vector_type(4)));
typedef unsigned int u32x2 __attribute__((ext_vector_type(2)));
typedef unsigned short u16x8 __attribute__((ext_vector_type(8)));
typedef unsigned short u16x4 __attribute__((ext_vector_type(4)));

#define DEV static __device__ __forceinline__

constexpr int BB = 2, TT = 2048, CC = 1024, HH = 16, DD = 64;
constexpr int MDIM = BB * TT;  // 4096

DEV u16 f2bf(float f) {
  unsigned int u = __builtin_bit_cast(unsigned int, f);
  u += 0x7fffu + ((u >> 16) & 1u);
  return (u16)(u >> 16);
}
DEV float bf2f(u16 h) {
  unsigned int u = ((unsigned int)h) << 16;
  return __builtin_bit_cast(float, u);
}
DEV void async16(const void* g, void* l) {
  __builtin_amdgcn_global_load_lds(
      (const __attribute__((address_space(1))) unsigned int*)g,
      (__attribute__((address_space(3))) unsigned int*)l, 16, 0, 0);
}
DEV void mfma16(f32x4& acc, u32x4 a, u32x4 b) {
  asm volatile("v_mfma_f32_16x16x32_bf16 %0, %1, %2, %0"
               : "+v"(acc)
               : "v"(a), "v"(b));
}
DEV void mfma32(f32x16& acc, u32x4 a, u32x4 b) {
  asm volatile("v_mfma_f32_32x32x16_bf16 %0, %1, %2, %0"
               : "+v"(acc)
               : "v"(a), "v"(b));
}
DEV u32 cvtpk(float lo, float hi) {
  u32 r;
  asm("v_cvt_pk_bf16_f32 %0, %1, %2" : "=v"(r) : "v"(lo), "v"(hi));
  return r;
}
DEV void pswap(u32& a, u32& b) {
#if __has_builtin(__builtin_amdgcn_permlane32_swap)
  u32x2 r = __builtin_amdgcn_permlane32_swap(a, b, false, false);
  a = r.x;
  b = r.y;
#else
  asm volatile("v_permlane32_swap_b32 %0, %1" : "+v"(a), "+v"(b));
#endif
}
DEV float exp2g(float x) {
#if __has_builtin(__builtin_amdgcn_exp2f)
  return __builtin_amdgcn_exp2f(x);
#else
  return exp2f(x);
#endif
}

// ---------------------------------------------------------------- prep ----
// One launch: W_attn transpose (bx<96), W_proj transpose (96<=bx<128),
// x f32->bf16 convert (bx>=128).
__global__ void prep_all(const float* __restrict__ x,
                         const float* __restrict__ Wa, const float* __restrict__ Wp,
                         u16* __restrict__ x_bf,
                         u16* __restrict__ Wa_t, u16* __restrict__ Wp_t) {
  __shared__ float tile[32][33];
  int bx = blockIdx.x;
  const int tx = threadIdx.x, ty = threadIdx.y;
  if (bx >= 128) {
    const int cb = (bx - 128) * 32 + blockIdx.y;
    const int i = (cb * 1024 + ty * 32 + tx) * 4;
    f32x4 v = *(const f32x4*)(x + i);
    u16x4 o;
#pragma unroll
    for (int j = 0; j < 4; ++j) o[j] = f2bf(v[j]);
    *(u16x4*)(x_bf + i) = o;
    return;
  }
  const float* in;
  u16* out;
  int Cc;
  if (bx < 96) { in = Wa; out = Wa_t; Cc = 3072; }
  else { bx -= 96; in = Wp; out = Wp_t; Cc = 1024; }
  const int R = 1024;
  const int x0 = bx * 32, y0 = blockIdx.y * 32;
  tile[ty][tx] = in[(size_t)(y0 + ty) * Cc + (x0 + tx)];
  __syncthreads();
  out[(size_t)(x0 + ty) * R + (y0 + tx)] = f2bf(tile[tx][ty]);
}

// -------------------------------------------------- qkv GEMM (256x256) ----
// T3/T4 schedule generalized from the PROVEN attn-R9 pipeline (not R7's
// drain-0 mistake): 256x256 tile, BK=64, 8 waves (2M x 4N), per-wave 128x64.
// LDS = 2 K-tiles x (A 32K + B 32K) = 128KB, organized as K-HALF slots.
// Per K-tile: pass kc=0 computes K 0..31 -> barrier (slot kh0 dead) ->
// STAGE(kt+2, kh0) overwrites it; pass kc=1 likewise. Top-of-iter wait is
// counted vmcnt(8) (= kt+1's outstanding loads), never 0 mid-loop.
// LDS swizzle: slot ^= (row>>1)&3 (2-way banks = free); source pre-swizzled
// (rule #21: both-sides-or-neither).
__global__ __launch_bounds__(512, 2) void gemm_qkv256(
    const u16* __restrict__ A, const u16* __restrict__ Bt,
    const float* __restrict__ bias,
    u16* __restrict__ qw, u16* __restrict__ kw, u16* __restrict__ vw) {
  extern __shared__ char smem[];  // A: 4 x 16KB | B: 4 x 16KB = 128KB
  const int K = CC, NT = K / 64;
  const int tid = threadIdx.x;
  const int lane = tid & 63, w = tid >> 6;  // 8 waves
  const int g = lane >> 4, c16 = lane & 15;
  const int wm2 = (w >> 2) * 128, wn2 = (w & 3) * 64;

  // bijective XCD patch swizzle: 192 blocks, 24/XCD as 3col x 8row patches
  const int wgid = blockIdx.x;
  const int xcd = wgid & 7, idx = wgid >> 3;
  const int bxs = (xcd & 3) * 3 + idx % 3;   // 0..11
  const int bys = (xcd >> 2) * 8 + idx / 3;  // 0..15
  const int brow = bys * 256, bcol = bxs * 256;

  // staging source swizzle: row = c*16 + (l>>2); slot = (l&3) ^ ((l>>3)&3)
  const int ssw = ((lane & 3) ^ ((lane >> 3) & 3)) << 4;
  // read swizzle: slot = g ^ ((c16>>1)&3)
  const int rsw = (g ^ ((c16 >> 1) & 3)) << 4;

  f32x4 acc[8][4];
#pragma unroll
  for (int m = 0; m < 8; ++m)
#pragma unroll
    for (int n = 0; n < 4; ++n) acc[m][n] = f32x4{0.f, 0.f, 0.f, 0.f};

  const size_t ldb = (size_t)K * 2;
  const char* Abase = (const char*)A + (size_t)brow * ldb;
  const char* Bbase = (const char*)Bt + (size_t)bcol * ldb;

  // STAGE one K-half of A and B for K-tile kt: 4 loads/thread (A2 + B2)
  auto STAGE = [&](int kt, int kh) {
    const int par = kt & 1;
    char* Adst = smem + (par * 2 + kh) * 16384;
    char* Bdst = smem + 65536 + (par * 2 + kh) * 16384;
    const size_t koff = (size_t)kt * 128 + kh * 64;
#pragma unroll
    for (int i = 0; i < 2; ++i) {
      const int c = w * 2 + i;                 // chunk 0..15 (16 rows each)
      const int row = c * 16 + (lane >> 2);
      async16(Abase + (size_t)row * ldb + koff + ssw, Adst + c * 1024);
      async16(Bbase + (size_t)row * ldb + koff + ssw, Bdst + c * 1024);
    }
  };

  STAGE(0, 0); STAGE(0, 1);
  STAGE(1, 0); STAGE(1, 1);

  for (int kt = 0; kt < NT; ++kt) {
    const int par = kt & 1;
    if (kt + 1 < NT)
      asm volatile("s_waitcnt vmcnt(8)" ::: "memory");  // kt fully landed
    else
      asm volatile("s_waitcnt vmcnt(0)" ::: "memory");
    __builtin_amdgcn_sched_barrier(0);
    __builtin_amdgcn_s_barrier();
    __builtin_amdgcn_sched_barrier(0);
#pragma unroll
    for (int kc = 0; kc < 2; ++kc) {
      const char* Ap = smem + (par * 2 + kc) * 16384;
      const char* Bp = smem + 65536 + (par * 2 + kc) * 16384;
      u32x4 af[8], bf[4];
#pragma unroll
      for (int m = 0; m < 8; ++m)
        af[m] = *(const u32x4*)(Ap + (wm2 + m * 16 + c16) * 64 + rsw);
#pragma unroll
      for (int n = 0; n < 4; ++n)
        bf[n] = *(const u32x4*)(Bp + (wn2 + n * 16 + c16) * 64 + rsw);
      asm volatile("s_waitcnt lgkmcnt(0)" ::: "memory");
      __builtin_amdgcn_sched_barrier(0);
      __builtin_amdgcn_s_setprio(1);
#pragma unroll
      for (int m = 0; m < 8; ++m)
#pragma unroll
        for (int n = 0; n < 4; ++n) mfma16(acc[m][n], af[m], bf[n]);
      __builtin_amdgcn_s_setprio(0);
      __builtin_amdgcn_s_barrier();         // all waves done reading kh=kc
      if (kt + 2 < NT) STAGE(kt + 2, kc);   // overwrite the dead slots
    }
  }

  // ---- epilogue: stage 256x256 bf16 tile in LDS (128KB), 16B stores ----
  u16* E = (u16*)smem;
  const int which = bcol >> 10;  // block entirely within q, k, or v
  if (which < 2) {
#pragma unroll
    for (int n = 0; n < 4; ++n) {
      const float bv = bias[bcol + wn2 + n * 16 + c16];
#pragma unroll
      for (int m = 0; m < 8; ++m)
#pragma unroll
        for (int r = 0; r < 4; ++r)
          E[(wm2 + m * 16 + g * 4 + r) * 256 + wn2 + n * 16 + c16] =
              f2bf(acc[m][n][r] + bv);
    }
  } else {  // v: stage transposed [col][row] so t becomes contiguous
#pragma unroll
    for (int n = 0; n < 4; ++n) {
      const float bv = bias[bcol + wn2 + n * 16 + c16];
#pragma unroll
      for (int m = 0; m < 8; ++m) {
        u16x4 t4;
#pragma unroll
        for (int r = 0; r < 4; ++r) t4[r] = f2bf(acc[m][n][r] + bv);
        *(u16x4*)&E[(wn2 + n * 16 + c16) * 256 + wm2 + m * 16 + g * 4] = t4;
      }
    }
  }
  __syncthreads();
#pragma unroll
  for (int i = 0; i < 16; ++i) {
    const int chunk = tid + i * 512;  // 8192 chunks of 16B
    if (which < 2) {
      const int row = chunk >> 5;           // 0..255
      const int col8 = (chunk & 31) * 8;
      const int colg = bcol + col8;
      const int c = colg & 1023, h = c >> 6, d = c & 63;
      const int rowg = brow + row, b = rowg >> 11, t = rowg & (TT - 1);
      u16x8 v8 = *(const u16x8*)&E[row * 256 + col8];
      u16* dst = (which == 0 ? qw : kw) + ((size_t)(b * HH + h) * TT + t) * DD + d;
      *(u16x8*)dst = v8;
    } else {
      const int drow = chunk >> 5;          // 0..255 (d direction)
      const int t8 = (chunk & 31) * 8;
      const int colg = bcol + drow;
      const int c = colg & 1023, h = c >> 6, d = c & 63;
      const int rowg = brow + t8, b = rowg >> 11, t = rowg & (TT - 1);
      u16x8 v8 = *(const u16x8*)&E[drow * 256 + t8];
      u16* dst = vw + ((size_t)(b * HH + h) * DD + d) * TT + t;
      *(u16x8*)dst = v8;
    }
  }
}

// ---------------------------------------------------------------- GEMM ----
// m97 structure (128x128, BK=64, 4 waves, single-buffer LDS) + XCD patch
// swizzle + LDS-coalesced fp32 epilogue. Used for proj only (grid 8x32 =
// exactly 1 block/CU; cross-block overlap does the pipelining).
__global__ __launch_bounds__(256) void gemm_proj(
    const u16* __restrict__ A, const u16* __restrict__ Bt,
    const float* __restrict__ bias, float* __restrict__ outF,
    int M, int N, int K) {
  __shared__ alignas(16) u16 Sh[2][128 * 64];
  u16* Asp = Sh[0];
  u16* Bsp = Sh[1];
  const int tid = threadIdx.x;
  const int lane = tid & 63, w = tid >> 6;
  const int g = lane >> 4, c16 = lane & 15;
  const int wm = (w >> 1) * 64, wn = (w & 1) * 64;

  const int wgid = blockIdx.y * gridDim.x + blockIdx.x;
  const int xcd = wgid & 7, pi = wgid >> 3;
  const int bxs = pi & 7;
  const int bys = 4 * xcd + (pi >> 3);
  const int brow = bys * 128, bcol = bxs * 128;

  const int lrow = lane >> 3;
  const int scol = ((lane & 7) ^ lrow) << 4;
  const int rswz = (c16 & 7) << 4;

  f32x4 acc[4][4];
#pragma unroll
  for (int m = 0; m < 4; ++m)
#pragma unroll
    for (int n = 0; n < 4; ++n) acc[m][n] = f32x4{0.f, 0.f, 0.f, 0.f};

  const size_t ldb = (size_t)K * 2;
  const char* Abase = (const char*)A + (size_t)brow * ldb;
  const char* Bbase = (const char*)Bt + (size_t)bcol * ldb;

  for (int kt = 0; kt < K; kt += 64) {
    __syncthreads();
#pragma unroll
    for (int i = 0; i < 4; ++i) {
      const int chunk = i * 4 + w;
      const int row = chunk * 8 + lrow;
      async16(Abase + (size_t)row * ldb + (size_t)kt * 2 + scol, (char*)Asp + chunk * 1024);
      async16(Bbase + (size_t)row * ldb + (size_t)kt * 2 + scol, (char*)Bsp + chunk * 1024);
    }
    __syncthreads();
#pragma unroll
    for (int kc = 0; kc < 2; ++kc) {
      const int cb = (kc * 64 + g * 16) ^ rswz;
      u32x4 af[4], bf8[4];
#pragma unroll
      for (int m = 0; m < 4; ++m)
        af[m] = *(const u32x4*)((const char*)Asp + (wm + m * 16 + c16) * 128 + cb);
#pragma unroll
      for (int n = 0; n < 4; ++n)
        bf8[n] = *(const u32x4*)((const char*)Bsp + (wn + n * 16 + c16) * 128 + cb);
#pragma unroll
      for (int m = 0; m < 4; ++m)
#pragma unroll
        for (int n = 0; n < 4; ++n) mfma16(acc[m][n], af[m], bf8[n]);
    }
  }

  float* Ef = (float*)&Sh[0][0];  // [64][128] f32
#pragma unroll
  for (int pass = 0; pass < 2; ++pass) {
    __syncthreads();
    if ((wm >> 6) == pass) {
#pragma unroll
      for (int n = 0; n < 4; ++n) {
        const float bv = bias[bcol + wn + n * 16 + c16];
#pragma unroll
        for (int m = 0; m < 4; ++m)
#pragma unroll
          for (int r = 0; r < 4; ++r)
            Ef[(m * 16 + g * 4 + r) * 128 + wn + n * 16 + c16] = acc[m][n][r] + bv;
      }
    }
    __syncthreads();
#pragma unroll
    for (int i = 0; i < 8; ++i) {
      const int chunk = tid + i * 256;
      const int row = chunk >> 5;
      const int c4 = (chunk & 31) * 4;
      f32x4 v4 = *(const f32x4*)&Ef[row * 128 + c4];
      *(f32x4*)&outF[(size_t)(brow + pass * 64 + row) * N + bcol + c4] = v4;
    }
  }
}

// ----------------------------------------------------------- attention ----
// R9 EXACT (proven 42.0us): swapped-operand flash attention, 32x32 MFMA,
// 4 waves x 32 q = 128-row block, 4-deep KV LDS, counted vmcnt,
// QK(t+1)-ahead in-wave pipeline, fixed-base softmax (scores bounded,
// softmax shift-invariant -> m=0 exact; no max tree / rescale).
__global__ __launch_bounds__(256) void attn_fwd(
    const u16* __restrict__ qw, const u16* __restrict__ kw,
    const u16* __restrict__ vw, u16* __restrict__ ao) {
  extern __shared__ u16 smem_a[];  // [4][64*64] K, then [4][64*64] V (64KB)
  const int tid = threadIdx.x;
  const int lane = tid & 63, w = tid >> 6;
  const int ql = lane & 31, half = lane >> 5;
  const int bh = blockIdx.y;
  const int qb = ((bh >> 4) & 1) ? (15 - blockIdx.x) : blockIdx.x;  // pairing
  const int q0w = qb * 128 + w * 32;
  const int qg = q0w + ql;
  const int lrow = lane >> 3;
  const int scol = ((lane & 7) ^ lrow) << 4;
  const int rswz = (ql & 7) << 4;

  u32x4 qf[4];
  {
    const u16* qrow = qw + ((size_t)bh * TT + qg) * DD;
    const float qs = 0.125f * 1.44269504f;
#pragma unroll
    for (int dwin = 0; dwin < 4; ++dwin) {
      u16x8 u = *(const u16x8*)(qrow + dwin * 16 + half * 8);
      u16x8 s;
#pragma unroll
      for (int j = 0; j < 8; ++j) s[j] = f2bf(bf2f(u[j]) * qs);
      qf[dwin] = __builtin_bit_cast(u32x4, s);
    }
  }

  f32x16 o0, o1;
#pragma unroll
  for (int i = 0; i < 16; ++i) { o0[i] = 0.f; o1[i] = 0.f; }
  float l_run = 0.f;

  const char* kbase = (const char*)kw + ((size_t)bh * TT) * 128;
  const char* vbase = (const char*)vw + ((size_t)bh * DD) * (TT * 2);

  const int nt = 2 * qb + 2;  // always even

  auto kptr = [&](int b) { return (char*)(smem_a + (b & 3) * 4096); };
  auto vptr = [&](int b) { return (char*)(smem_a + 16384 + (b & 3) * 4096); };

  auto STAGE = [&](int kt_) {
    if (kt_ >= nt) return;
    const int t0_ = kt_ * 64;
#pragma unroll
    for (int i_ = 0; i_ < 2; ++i_) {
      const int chunk = w * 2 + i_;
      const int row = chunk * 8 + lrow;
      async16(kbase + (size_t)(t0_ + row) * 128 + scol, kptr(kt_) + chunk * 1024);
      async16(vbase + (size_t)row * (TT * 2) + (size_t)t0_ * 2 + scol,
              vptr(kt_) + chunk * 1024);
    }
  };

  auto QK = [&](int kt_, f32x16& sa, f32x16& sb) {
    const char* Kc = kptr(kt_);
#pragma unroll
    for (int i = 0; i < 16; ++i) { sa[i] = 0.f; sb[i] = 0.f; }
    __builtin_amdgcn_s_setprio(1);
#pragma unroll
    for (int dwin = 0; dwin < 4; ++dwin) {
      const int cb = (dwin * 32 + half * 16) ^ rswz;
      u32x4 ak0 = *(const u32x4*)(Kc + (0 + ql) * 128 + cb);
      u32x4 ak1 = *(const u32x4*)(Kc + (32 + ql) * 128 + cb);
      mfma32(sa, ak0, qf[dwin]);
      mfma32(sb, ak1, qf[dwin]);
    }
    __builtin_amdgcn_s_setprio(0);
  };

  auto FINISH = [&](int kt_, f32x16& s0, f32x16& s1) {
    const int t0 = kt_ * 64;
    if (t0 >= q0w + 32) return;
    if (t0 + 63 > q0w) {
      const int kb = t0 + 4 * half - qg;
#pragma unroll
      for (int r = 0; r < 16; ++r) {
        const int ko = (r & 3) + 8 * (r >> 2);
        if (kb + ko > 0) s0[r] = -1e30f;
        if (kb + 32 + ko > 0) s1[r] = -1e30f;
      }
    }
#pragma unroll
    for (int i = 0; i < 16; ++i) {
      s0[i] = exp2g(s0[i]);
      s1[i] = exp2g(s1[i]);
    }
    float a8[8];
#pragma unroll
    for (int i = 0; i < 8; ++i)
      a8[i] = (s0[i] + s0[i + 8]) + (s1[i] + s1[i + 8]);
    float rs = ((a8[0] + a8[1]) + (a8[2] + a8[3])) + ((a8[4] + a8[5]) + (a8[6] + a8[7]));
    rs += __shfl_xor(rs, 32, 64);
    l_run += rs;

    u32x4 pf[4];
#pragma unroll
    for (int win = 0; win < 4; ++win) {
      const int b = (win & 1) * 8;
      u32 w0, w1, w2, w3;
      if (win < 2) {
        w0 = cvtpk(s0[b + 0], s0[b + 1]); w2 = cvtpk(s0[b + 4], s0[b + 5]);
        w1 = cvtpk(s0[b + 2], s0[b + 3]); w3 = cvtpk(s0[b + 6], s0[b + 7]);
      } else {
        w0 = cvtpk(s1[b + 0], s1[b + 1]); w2 = cvtpk(s1[b + 4], s1[b + 5]);
        w1 = cvtpk(s1[b + 2], s1[b + 3]); w3 = cvtpk(s1[b + 6], s1[b + 7]);
      }
      pswap(w0, w2);
      pswap(w1, w3);
      pf[win] = u32x4{w0, w1, w2, w3};
    }
    const char* Vc = vptr(kt_);
    __builtin_amdgcn_s_setprio(1);
#pragma unroll
    for (int win = 0; win < 4; ++win) {
      const int cb = (win * 32 + half * 16) ^ rswz;
      u32x4 av0 = *(const u32x4*)(Vc + (0 + ql) * 128 + cb);
      u32x4 av1 = *(const u32x4*)(Vc + (32 + ql) * 128 + cb);
      mfma32(o0, av0, pf[win]);
      mfma32(o1, av1, pf[win]);
    }
    __builtin_amdgcn_s_setprio(0);
  };

  STAGE(0);
  STAGE(1);
  STAGE(2);
  if (nt >= 3)
    asm volatile("s_waitcnt vmcnt(8)" ::: "memory");
  else
    asm volatile("s_waitcnt vmcnt(4)" ::: "memory");
  __builtin_amdgcn_sched_barrier(0);
  __builtin_amdgcn_s_barrier();
  __builtin_amdgcn_sched_barrier(0);

  f32x16 sA0, sA1, sB0, sB1;
  QK(0, sA0, sA1);

#define BODY(KT, C0, C1, N0, N1)                                          \
  {                                                                       \
    const int kt_b = (KT);                                                \
    if (kt_b + 2 < nt)                                                    \
      asm volatile("s_waitcnt vmcnt(4)" ::: "memory");                    \
    else                                                                  \
      asm volatile("s_waitcnt vmcnt(0)" ::: "memory");                    \
    __builtin_amdgcn_sched_barrier(0);                                    \
    __builtin_amdgcn_s_barrier();                                         \
    __builtin_amdgcn_sched_barrier(0);                                    \
    STAGE(kt_b + 3);                                                      \
    if (kt_b + 1 < nt && (kt_b + 1) * 64 < q0w + 32) QK(kt_b + 1, N0, N1);\
    FINISH(kt_b, C0, C1);                                                 \
  }

  for (int kt2 = 0; kt2 < nt; kt2 += 2) {
    BODY(kt2, sA0, sA1, sB0, sB1);
    BODY(kt2 + 1, sB0, sB1, sA0, sA1);
  }
#undef BODY

  const int b = bh >> 4, h = bh & 15;
  const float inv = 1.f / l_run;
  u16* aorow = ao + ((size_t)(b * TT) + qg) * CC + h * DD;
#pragma unroll
  for (int rg = 0; rg < 4; ++rg) {
    u16x4 t0v, t1v;
#pragma unroll
    for (int j = 0; j < 4; ++j) {
      t0v[j] = f2bf(o0[rg * 4 + j] * inv);
      t1v[j] = f2bf(o1[rg * 4 + j] * inv);
    }
    *(u16x4*)(aorow + 8 * rg + 4 * half) = t0v;
    *(u16x4*)(aorow + 32 + 8 * rg + 4 * half) = t1v;
  }
}

// -------------------------------------------------------------- launch ----
extern "C" void kernel_launch(void* const* d_in, const int* in_sizes, int n_in,
                              void* d_out, int out_size, void* d_ws, size_t ws_size,
                              hipStream_t stream) {
  const float* x  = (const float*)d_in[0];
  const float* Wa = (const float*)d_in[1];
  const float* ba = (const float*)d_in[2];
  const float* Wp = (const float*)d_in[3];
  const float* bp = (const float*)d_in[4];
  float* out = (float*)d_out;

  char* ws = (char*)d_ws;
  const size_t MB = 1ull << 20;
  u16* x_bf = (u16*)(ws);            // 8 MB  [4096][1024]
  u16* ao   = (u16*)(ws);            // 8 MB  alias (x_bf dead after QKV GEMM)
  u16* Wa_t = (u16*)(ws + 8 * MB);   // 6 MB  [3072][1024]
  u16* Wp_t = (u16*)(ws + 14 * MB);  // 2 MB  [1024][1024]
  u16* q_ws = (u16*)(ws + 16 * MB);  // 8 MB  [32][2048][64]
  u16* k_ws = (u16*)(ws + 24 * MB);  // 8 MB  [32][2048][64]
  u16* v_ws = (u16*)(ws + 32 * MB);  // 8 MB  [32][64][2048]

  // opt-in to 128KB dynamic LDS for the 256^2 GEMM (idempotent, graph-safe)
  static bool attr_set = []() {
    hipFuncSetAttribute((const void*)gemm_qkv256,
                        hipFuncAttributeMaxDynamicSharedMemorySize, 131072);
    hipFuncSetAttribute((const void*)attn_fwd,
                        hipFuncAttributeMaxDynamicSharedMemorySize, 65536);
    return true;
  }();
  (void)attr_set;

  hipLaunchKernelGGL(prep_all, dim3(160, 32), dim3(32, 32), 0, stream,
                     x, Wa, Wp, x_bf, Wa_t, Wp_t);
  hipLaunchKernelGGL(gemm_qkv256, dim3(192), dim3(512), 131072, stream,
                     x_bf, Wa_t, ba, q_ws, k_ws, v_ws);
  hipLaunchKernelGGL(attn_fwd, dim3(TT / 128, BB * HH), dim3(256), 65536, stream,
                     q_ws, k_ws, v_ws, ao);
  hipLaunchKernelGGL(gemm_proj, dim3(CC / 128, MDIM / 128), dim3(256), 0, stream,
                     ao, Wp_t, bp, out, MDIM, CC, CC);
}

// Round 14
// 107.988 us; speedup vs baseline: 1.0874x; 1.0248x over previous
//
#include <hip/hip_runtime.h>

typedef unsigned short u16;
typedef unsigned int u32;
typedef float f32x4 __attribute__((ext_vector_type(4)));
typedef float f32x16 __attribute__((ext_vector_type(16)));
typedef unsigned int u32x4 __attribute__((ext_vector_type(4)));
typedef unsigned int u32x2 __attribute__((ext_vector_type(2)));
typedef unsigned short u16x8 __attribute__((ext_vector_type(8)));
typedef unsigned short u16x4 __attribute__((ext_vector_type(4)));

#define DEV static __device__ __forceinline__

constexpr int BB = 2, TT = 2048, CC = 1024, HH = 16, DD = 64;
constexpr int MDIM = BB * TT;  // 4096

DEV u16 f2bf(float f) {
  unsigned int u = __builtin_bit_cast(unsigned int, f);
  u += 0x7fffu + ((u >> 16) & 1u);
  return (u16)(u >> 16);
}
DEV float bf2f(u16 h) {
  unsigned int u = ((unsigned int)h) << 16;
  return __builtin_bit_cast(float, u);
}
DEV void async16(const void* g, void* l) {
  __builtin_amdgcn_global_load_lds(
      (const __attribute__((address_space(1))) unsigned int*)g,
      (__attribute__((address_space(3))) unsigned int*)l, 16, 0, 0);
}
DEV void mfma16(f32x4& acc, u32x4 a, u32x4 b) {
  asm volatile("v_mfma_f32_16x16x32_bf16 %0, %1, %2, %0"
               : "+v"(acc)
               : "v"(a), "v"(b));
}
DEV void mfma32(f32x16& acc, u32x4 a, u32x4 b) {
  asm volatile("v_mfma_f32_32x32x16_bf16 %0, %1, %2, %0"
               : "+v"(acc)
               : "v"(a), "v"(b));
}
DEV u32 cvtpk(float lo, float hi) {
  u32 r;
  asm("v_cvt_pk_bf16_f32 %0, %1, %2" : "=v"(r) : "v"(lo), "v"(hi));
  return r;
}
DEV void pswap(u32& a, u32& b) {
#if __has_builtin(__builtin_amdgcn_permlane32_swap)
  u32x2 r = __builtin_amdgcn_permlane32_swap(a, b, false, false);
  a = r.x;
  b = r.y;
#else
  asm volatile("v_permlane32_swap_b32 %0, %1" : "+v"(a), "+v"(b));
#endif
}
DEV float exp2g(float x) {
#if __has_builtin(__builtin_amdgcn_exp2f)
  return __builtin_amdgcn_exp2f(x);
#else
  return exp2f(x);
#endif
}

// ---------------------------------------------------------------- prep ----
__global__ void prep_all(const float* __restrict__ x,
                         const float* __restrict__ Wa, const float* __restrict__ Wp,
                         u16* __restrict__ x_bf,
                         u16* __restrict__ Wa_t, u16* __restrict__ Wp_t) {
  __shared__ float tile[32][33];
  int bx = blockIdx.x;
  const int tx = threadIdx.x, ty = threadIdx.y;
  if (bx >= 128) {
    const int cb = (bx - 128) * 32 + blockIdx.y;
    const int i = (cb * 1024 + ty * 32 + tx) * 4;
    f32x4 v = *(const f32x4*)(x + i);
    u16x4 o;
#pragma unroll
    for (int j = 0; j < 4; ++j) o[j] = f2bf(v[j]);
    *(u16x4*)(x_bf + i) = o;
    return;
  }
  const float* in;
  u16* out;
  int Cc;
  if (bx < 96) { in = Wa; out = Wa_t; Cc = 3072; }
  else { bx -= 96; in = Wp; out = Wp_t; Cc = 1024; }
  const int R = 1024;
  const int x0 = bx * 32, y0 = blockIdx.y * 32;
  tile[ty][tx] = in[(size_t)(y0 + ty) * Cc + (x0 + tx)];
  __syncthreads();
  out[(size_t)(x0 + ty) * R + (y0 + tx)] = f2bf(tile[tx][ty]);
}

// -------------------------------------------------- qkv GEMM (256x192) ----
// R12's proven counted-vmcnt schedule, retiled 256x256 -> 256x192 so the
// grid is 16x16 = 256 blocks = EXACTLY 1/CU (R12's 192 blocks left 25% of
// the chip idle). 8 waves (2M x 4N), per-wave 128x48, BK=64.
// LDS: 2-deep full-K-tile buffers, A 2x32KB + B 2x24KB = 112KB.
// Per iter: counted vmcnt(7) [stage(kt+1) stays in flight, never 0 mid-loop]
// -> barrier -> compute both K-halves -> barrier -> stage(kt+2) into the
// retired buffer. Same m97 chunk geometry + XOR swizzle as proven kernels.
__global__ __launch_bounds__(512, 2) void gemm_qkv256(
    const u16* __restrict__ A, const u16* __restrict__ Bt,
    const float* __restrict__ bias,
    u16* __restrict__ qw, u16* __restrict__ kw, u16* __restrict__ vw) {
  extern __shared__ char smem[];  // A: 2x32KB @0 | B: 2x24KB @64KB = 112KB
  const int K = CC, NT = K / 64;
  const int tid = threadIdx.x;
  const int lane = tid & 63, w = tid >> 6;  // 8 waves
  const int g = lane >> 4, c16 = lane & 15;
  const int wm2 = (w >> 2) * 128, wn2 = (w & 3) * 48;

  // bijective XCD patch swizzle: 16 patches of 4row x 4col tiles; XCD gets 2.
  const int wgid = blockIdx.x;
  const int xcd = wgid & 7, idx = wgid >> 3;       // idx 0..31
  const int patch = xcd * 2 + (idx >> 4);          // 0..15
  const int q = idx & 15;
  const int bys = (patch & 3) * 4 + (q & 3);       // 0..15
  const int bxs = (patch >> 2) * 4 + (q >> 2);     // 0..15
  const int brow = bys * 256, bcol = bxs * 192;

  const int lrow = lane >> 3;
  const int scol = ((lane & 7) ^ lrow) << 4;  // source pre-swizzle
  const int rswz = (c16 & 7) << 4;            // read swizzle

  f32x4 acc[8][3];
#pragma unroll
  for (int m = 0; m < 8; ++m)
#pragma unroll
    for (int n = 0; n < 3; ++n) acc[m][n] = f32x4{0.f, 0.f, 0.f, 0.f};

  const size_t ldb = (size_t)K * 2;
  const char* Abase = (const char*)A + (size_t)brow * ldb;
  const char* Bbase = (const char*)Bt + (size_t)bcol * ldb;

  // stage full K-tile kt into buffer par: A 4 chunks/wave, B 3 chunks/wave
  auto STAGE = [&](int kt) {
    const int par = kt & 1;
    char* Adst = smem + par * 32768;
    char* Bdst = smem + 65536 + par * 24576;
    const size_t koff = (size_t)kt * 128;
#pragma unroll
    for (int i = 0; i < 4; ++i) {
      const int c = w * 4 + i;            // A chunk 0..31 (8 rows each)
      const int row = c * 8 + lrow;
      async16(Abase + (size_t)row * ldb + koff + scol, Adst + c * 1024);
    }
#pragma unroll
    for (int i = 0; i < 3; ++i) {
      const int c = w * 3 + i;            // B chunk 0..23
      const int row = c * 8 + lrow;
      async16(Bbase + (size_t)row * ldb + koff + scol, Bdst + c * 1024);
    }
  };

  STAGE(0);
  STAGE(1);

  for (int kt = 0; kt < NT; ++kt) {
    const int par = kt & 1;
    if (kt + 1 < NT)
      asm volatile("s_waitcnt vmcnt(7)" ::: "memory");  // kt landed; kt+1 in flight
    else
      asm volatile("s_waitcnt vmcnt(0)" ::: "memory");
    __builtin_amdgcn_sched_barrier(0);
    __builtin_amdgcn_s_barrier();
    __builtin_amdgcn_sched_barrier(0);
    const char* Ap = smem + par * 32768;
    const char* Bp = smem + 65536 + par * 24576;
#pragma unroll
    for (int kc = 0; kc < 2; ++kc) {
      const int cb = (kc * 64 + g * 16) ^ rswz;
      u32x4 af[8], bf[3];
#pragma unroll
      for (int m = 0; m < 8; ++m)
        af[m] = *(const u32x4*)(Ap + (wm2 + m * 16 + c16) * 128 + cb);
#pragma unroll
      for (int n = 0; n < 3; ++n)
        bf[n] = *(const u32x4*)(Bp + (wn2 + n * 16 + c16) * 128 + cb);
      asm volatile("s_waitcnt lgkmcnt(0)" ::: "memory");
      __builtin_amdgcn_sched_barrier(0);
      __builtin_amdgcn_s_setprio(1);
#pragma unroll
      for (int m = 0; m < 8; ++m)
#pragma unroll
        for (int n = 0; n < 3; ++n) mfma16(acc[m][n], af[m], bf[n]);
      __builtin_amdgcn_s_setprio(0);
    }
    __builtin_amdgcn_s_barrier();       // all waves done reading buf[par]
    if (kt + 2 < NT) STAGE(kt + 2);     // overwrite the retired buffer
  }

  // ---- epilogue: stage [256][192] u16 (96KB) then 16B coalesced stores ----
  u16* E = (u16*)smem;
#pragma unroll
  for (int n = 0; n < 3; ++n) {
    const float bv = bias[bcol + wn2 + n * 16 + c16];
#pragma unroll
    for (int m = 0; m < 8; ++m)
#pragma unroll
      for (int r = 0; r < 4; ++r)
        E[(wm2 + m * 16 + g * 4 + r) * 192 + wn2 + n * 16 + c16] =
            f2bf(acc[m][n][r] + bv);
  }
  __syncthreads();
  // dual-interpretation chunk loop: 6144 ids, each checked under both the
  // row-major (q/k) and col-major (v) interpretation; union covers the tile
  // exactly once (col boundaries 1024/2048 are 8-aligned).
#pragma unroll
  for (int i = 0; i < 12; ++i) {
    const int c = tid + i * 512;
    {  // row-major: 1 row x 8 cols -> q or k
      const int row = c / 24, col8 = (c % 24) * 8;
      const int colg = bcol + col8;
      if (colg < 2048) {
        const int which = colg >> 10, cc = colg & 1023, h = cc >> 6, d = cc & 63;
        const int rowg = brow + row, b = rowg >> 11, t = rowg & (TT - 1);
        u16x8 v8 = *(const u16x8*)&E[row * 192 + col8];
        u16* dst = (which == 0 ? qw : kw) + ((size_t)(b * HH + h) * TT + t) * DD + d;
        *(u16x8*)dst = v8;
      }
    }
    {  // col-major: 8 rows x 1 col -> v (stored [d][t])
      const int col = c % 192, row8 = (c / 192) * 8;
      const int colg = bcol + col;
      if (colg >= 2048) {
        const int cc = colg & 1023, h = cc >> 6, d = cc & 63;
        const int rowg = brow + row8, b = rowg >> 11, t = rowg & (TT - 1);
        u16x8 v8;
#pragma unroll
        for (int j = 0; j < 8; ++j) v8[j] = E[(row8 + j) * 192 + col];
        u16* dst = vw + ((size_t)(b * HH + h) * DD + d) * TT + t;
        *(u16x8*)dst = v8;
      }
    }
  }
}

// ----------------------------------------------------------- proj GEMM ----
// m97 structure (128x128, BK=64, 4 waves, single-buffer LDS) + XCD patch
// swizzle + LDS-coalesced fp32 epilogue. Grid 8x32 = 256 = 1 block/CU.
__global__ __launch_bounds__(256) void gemm_proj(
    const u16* __restrict__ A, const u16* __restrict__ Bt,
    const float* __restrict__ bias, float* __restrict__ outF,
    int M, int N, int K) {
  __shared__ alignas(16) u16 Sh[2][128 * 64];
  u16* Asp = Sh[0];
  u16* Bsp = Sh[1];
  const int tid = threadIdx.x;
  const int lane = tid & 63, w = tid >> 6;
  const int g = lane >> 4, c16 = lane & 15;
  const int wm = (w >> 1) * 64, wn = (w & 1) * 64;

  const int wgid = blockIdx.y * gridDim.x + blockIdx.x;
  const int xcd = wgid & 7, pi = wgid >> 3;
  const int bxs = pi & 7;
  const int bys = 4 * xcd + (pi >> 3);
  const int brow = bys * 128, bcol = bxs * 128;

  const int lrow = lane >> 3;
  const int scol = ((lane & 7) ^ lrow) << 4;
  const int rswz = (c16 & 7) << 4;

  f32x4 acc[4][4];
#pragma unroll
  for (int m = 0; m < 4; ++m)
#pragma unroll
    for (int n = 0; n < 4; ++n) acc[m][n] = f32x4{0.f, 0.f, 0.f, 0.f};

  const size_t ldb = (size_t)K * 2;
  const char* Abase = (const char*)A + (size_t)brow * ldb;
  const char* Bbase = (const char*)Bt + (size_t)bcol * ldb;

  for (int kt = 0; kt < K; kt += 64) {
    __syncthreads();
#pragma unroll
    for (int i = 0; i < 4; ++i) {
      const int chunk = i * 4 + w;
      const int row = chunk * 8 + lrow;
      async16(Abase + (size_t)row * ldb + (size_t)kt * 2 + scol, (char*)Asp + chunk * 1024);
      async16(Bbase + (size_t)row * ldb + (size_t)kt * 2 + scol, (char*)Bsp + chunk * 1024);
    }
    __syncthreads();
#pragma unroll
    for (int kc = 0; kc < 2; ++kc) {
      const int cb = (kc * 64 + g * 16) ^ rswz;
      u32x4 af[4], bf8[4];
#pragma unroll
      for (int m = 0; m < 4; ++m)
        af[m] = *(const u32x4*)((const char*)Asp + (wm + m * 16 + c16) * 128 + cb);
#pragma unroll
      for (int n = 0; n < 4; ++n)
        bf8[n] = *(const u32x4*)((const char*)Bsp + (wn + n * 16 + c16) * 128 + cb);
#pragma unroll
      for (int m = 0; m < 4; ++m)
#pragma unroll
        for (int n = 0; n < 4; ++n) mfma16(acc[m][n], af[m], bf8[n]);
    }
  }

  float* Ef = (float*)&Sh[0][0];  // [64][128] f32
#pragma unroll
  for (int pass = 0; pass < 2; ++pass) {
    __syncthreads();
    if ((wm >> 6) == pass) {
#pragma unroll
      for (int n = 0; n < 4; ++n) {
        const float bv = bias[bcol + wn + n * 16 + c16];
#pragma unroll
        for (int m = 0; m < 4; ++m)
#pragma unroll
          for (int r = 0; r < 4; ++r)
            Ef[(m * 16 + g * 4 + r) * 128 + wn + n * 16 + c16] = acc[m][n][r] + bv;
      }
    }
    __syncthreads();
#pragma unroll
    for (int i = 0; i < 8; ++i) {
      const int chunk = tid + i * 256;
      const int row = chunk >> 5;
      const int c4 = (chunk & 31) * 4;
      f32x4 v4 = *(const f32x4*)&Ef[row * 128 + c4];
      *(f32x4*)&outF[(size_t)(brow + pass * 64 + row) * N + bcol + c4] = v4;
    }
  }
}

// ----------------------------------------------------------- attention ----
// R9 EXACT (proven 42.0us): swapped-operand flash attention, 32x32 MFMA,
// 4 waves x 32 q = 128-row block, 4-deep KV LDS, counted vmcnt,
// QK(t+1)-ahead in-wave pipeline, fixed-base softmax.
__global__ __launch_bounds__(256) void attn_fwd(
    const u16* __restrict__ qw, const u16* __restrict__ kw,
    const u16* __restrict__ vw, u16* __restrict__ ao) {
  extern __shared__ u16 smem_a[];  // [4][64*64] K, then [4][64*64] V (64KB)
  const int tid = threadIdx.x;
  const int lane = tid & 63, w = tid >> 6;
  const int ql = lane & 31, half = lane >> 5;
  const int bh = blockIdx.y;
  const int qb = ((bh >> 4) & 1) ? (15 - blockIdx.x) : blockIdx.x;  // pairing
  const int q0w = qb * 128 + w * 32;
  const int qg = q0w + ql;
  const int lrow = lane >> 3;
  const int scol = ((lane & 7) ^ lrow) << 4;
  const int rswz = (ql & 7) << 4;

  u32x4 qf[4];
  {
    const u16* qrow = qw + ((size_t)bh * TT + qg) * DD;
    const float qs = 0.125f * 1.44269504f;
#pragma unroll
    for (int dwin = 0; dwin < 4; ++dwin) {
      u16x8 u = *(const u16x8*)(qrow + dwin * 16 + half * 8);
      u16x8 s;
#pragma unroll
      for (int j = 0; j < 8; ++j) s[j] = f2bf(bf2f(u[j]) * qs);
      qf[dwin] = __builtin_bit_cast(u32x4, s);
    }
  }

  f32x16 o0, o1;
#pragma unroll
  for (int i = 0; i < 16; ++i) { o0[i] = 0.f; o1[i] = 0.f; }
  float l_run = 0.f;

  const char* kbase = (const char*)kw + ((size_t)bh * TT) * 128;
  const char* vbase = (const char*)vw + ((size_t)bh * DD) * (TT * 2);

  const int nt = 2 * qb + 2;  // always even

  auto kptr = [&](int b) { return (char*)(smem_a + (b & 3) * 4096); };
  auto vptr = [&](int b) { return (char*)(smem_a + 16384 + (b & 3) * 4096); };

  auto STAGE = [&](int kt_) {
    if (kt_ >= nt) return;
    const int t0_ = kt_ * 64;
#pragma unroll
    for (int i_ = 0; i_ < 2; ++i_) {
      const int chunk = w * 2 + i_;
      const int row = chunk * 8 + lrow;
      async16(kbase + (size_t)(t0_ + row) * 128 + scol, kptr(kt_) + chunk * 1024);
      async16(vbase + (size_t)row * (TT * 2) + (size_t)t0_ * 2 + scol,
              vptr(kt_) + chunk * 1024);
    }
  };

  auto QK = [&](int kt_, f32x16& sa, f32x16& sb) {
    const char* Kc = kptr(kt_);
#pragma unroll
    for (int i = 0; i < 16; ++i) { sa[i] = 0.f; sb[i] = 0.f; }
    __builtin_amdgcn_s_setprio(1);
#pragma unroll
    for (int dwin = 0; dwin < 4; ++dwin) {
      const int cb = (dwin * 32 + half * 16) ^ rswz;
      u32x4 ak0 = *(const u32x4*)(Kc + (0 + ql) * 128 + cb);
      u32x4 ak1 = *(const u32x4*)(Kc + (32 + ql) * 128 + cb);
      mfma32(sa, ak0, qf[dwin]);
      mfma32(sb, ak1, qf[dwin]);
    }
    __builtin_amdgcn_s_setprio(0);
  };

  auto FINISH = [&](int kt_, f32x16& s0, f32x16& s1) {
    const int t0 = kt_ * 64;
    if (t0 >= q0w + 32) return;
    if (t0 + 63 > q0w) {
      const int kb = t0 + 4 * half - qg;
#pragma unroll
      for (int r = 0; r < 16; ++r) {
        const int ko = (r & 3) + 8 * (r >> 2);
        if (kb + ko > 0) s0[r] = -1e30f;
        if (kb + 32 + ko > 0) s1[r] = -1e30f;
      }
    }
#pragma unroll
    for (int i = 0; i < 16; ++i) {
      s0[i] = exp2g(s0[i]);
      s1[i] = exp2g(s1[i]);
    }
    float a8[8];
#pragma unroll
    for (int i = 0; i < 8; ++i)
      a8[i] = (s0[i] + s0[i + 8]) + (s1[i] + s1[i + 8]);
    float rs = ((a8[0] + a8[1]) + (a8[2] + a8[3])) + ((a8[4] + a8[5]) + (a8[6] + a8[7]));
    rs += __shfl_xor(rs, 32, 64);
    l_run += rs;

    u32x4 pf[4];
#pragma unroll
    for (int win = 0; win < 4; ++win) {
      const int b = (win & 1) * 8;
      u32 w0, w1, w2, w3;
      if (win < 2) {
        w0 = cvtpk(s0[b + 0], s0[b + 1]); w2 = cvtpk(s0[b + 4], s0[b + 5]);
        w1 = cvtpk(s0[b + 2], s0[b + 3]); w3 = cvtpk(s0[b + 6], s0[b + 7]);
      } else {
        w0 = cvtpk(s1[b + 0], s1[b + 1]); w2 = cvtpk(s1[b + 4], s1[b + 5]);
        w1 = cvtpk(s1[b + 2], s1[b + 3]); w3 = cvtpk(s1[b + 6], s1[b + 7]);
      }
      pswap(w0, w2);
      pswap(w1, w3);
      pf[win] = u32x4{w0, w1, w2, w3};
    }
    const char* Vc = vptr(kt_);
    __builtin_amdgcn_s_setprio(1);
#pragma unroll
    for (int win = 0; win < 4; ++win) {
      const int cb = (win * 32 + half * 16) ^ rswz;
      u32x4 av0 = *(const u32x4*)(Vc + (0 + ql) * 128 + cb);
      u32x4 av1 = *(const u32x4*)(Vc + (32 + ql) * 128 + cb);
      mfma32(o0, av0, pf[win]);
      mfma32(o1, av1, pf[win]);
    }
    __builtin_amdgcn_s_setprio(0);
  };

  STAGE(0);
  STAGE(1);
  STAGE(2);
  if (nt >= 3)
    asm volatile("s_waitcnt vmcnt(8)" ::: "memory");
  else
    asm volatile("s_waitcnt vmcnt(4)" ::: "memory");
  __builtin_amdgcn_sched_barrier(0);
  __builtin_amdgcn_s_barrier();
  __builtin_amdgcn_sched_barrier(0);

  f32x16 sA0, sA1, sB0, sB1;
  QK(0, sA0, sA1);

#define BODY(KT, C0, C1, N0, N1)                                          \
  {                                                                       \
    const int kt_b = (KT);                                                \
    if (kt_b + 2 < nt)                                                    \
      asm volatile("s_waitcnt vmcnt(4)" ::: "memory");                    \
    else                                                                  \
      asm volatile("s_waitcnt vmcnt(0)" ::: "memory");                    \
    __builtin_amdgcn_sched_barrier(0);                                    \
    __builtin_amdgcn_s_barrier();                                         \
    __builtin_amdgcn_sched_barrier(0);                                    \
    STAGE(kt_b + 3);                                                      \
    if (kt_b + 1 < nt && (kt_b + 1) * 64 < q0w + 32) QK(kt_b + 1, N0, N1);\
    FINISH(kt_b, C0, C1);                                                 \
  }

  for (int kt2 = 0; kt2 < nt; kt2 += 2) {
    BODY(kt2, sA0, sA1, sB0, sB1);
    BODY(kt2 + 1, sB0, sB1, sA0, sA1);
  }
#undef BODY

  const int b = bh >> 4, h = bh & 15;
  const float inv = 1.f / l_run;
  u16* aorow = ao + ((size_t)(b * TT) + qg) * CC + h * DD;
#pragma unroll
  for (int rg = 0; rg < 4; ++rg) {
    u16x4 t0v, t1v;
#pragma unroll
    for (int j = 0; j < 4; ++j) {
      t0v[j] = f2bf(o0[rg * 4 + j] * inv);
      t1v[j] = f2bf(o1[rg * 4 + j] * inv);
    }
    *(u16x4*)(aorow + 8 * rg + 4 * half) = t0v;
    *(u16x4*)(aorow + 32 + 8 * rg + 4 * half) = t1v;
  }
}

// -------------------------------------------------------------- launch ----
extern "C" void kernel_launch(void* const* d_in, const int* in_sizes, int n_in,
                              void* d_out, int out_size, void* d_ws, size_t ws_size,
                              hipStream_t stream) {
  const float* x  = (const float*)d_in[0];
  const float* Wa = (const float*)d_in[1];
  const float* ba = (const float*)d_in[2];
  const float* Wp = (const float*)d_in[3];
  const float* bp = (const float*)d_in[4];
  float* out = (float*)d_out;

  char* ws = (char*)d_ws;
  const size_t MB = 1ull << 20;
  u16* x_bf = (u16*)(ws);            // 8 MB  [4096][1024]
  u16* ao   = (u16*)(ws);            // 8 MB  alias (x_bf dead after QKV GEMM)
  u16* Wa_t = (u16*)(ws + 8 * MB);   // 6 MB  [3072][1024]
  u16* Wp_t = (u16*)(ws + 14 * MB);  // 2 MB  [1024][1024]
  u16* q_ws = (u16*)(ws + 16 * MB);  // 8 MB  [32][2048][64]
  u16* k_ws = (u16*)(ws + 24 * MB);  // 8 MB  [32][2048][64]
  u16* v_ws = (u16*)(ws + 32 * MB);  // 8 MB  [32][64][2048]

  static bool attr_set = []() {
    hipFuncSetAttribute((const void*)gemm_qkv256,
                        hipFuncAttributeMaxDynamicSharedMemorySize, 114688);
    hipFuncSetAttribute((const void*)attn_fwd,
                        hipFuncAttributeMaxDynamicSharedMemorySize, 65536);
    return true;
  }();
  (void)attr_set;

  hipLaunchKernelGGL(prep_all, dim3(160, 32), dim3(32, 32), 0, stream,
                     x, Wa, Wp, x_bf, Wa_t, Wp_t);
  hipLaunchKernelGGL(gemm_qkv256, dim3(256), dim3(512), 114688, stream,
                     x_bf, Wa_t, ba, q_ws, k_ws, v_ws);
  hipLaunchKernelGGL(attn_fwd, dim3(TT / 128, BB * HH), dim3(256), 65536, stream,
                     q_ws, k_ws, v_ws, ao);
  hipLaunchKernelGGL(gemm_proj, dim3(CC / 128, MDIM / 128), dim3(256), 0, stream,
                     ao, Wp_t, bp, out, MDIM, CC, CC);
}